// Round 19
// baseline (324.609 us; speedup 1.0000x reference)
//
#include <hip/hip_runtime.h>

typedef unsigned long long u64;
typedef unsigned int u32;
typedef unsigned short ushort_t;

using f32x16 = __attribute__((ext_vector_type(16))) float;
using f32x4  = __attribute__((ext_vector_type(4))) float;
using short8 = __attribute__((ext_vector_type(8))) short;

#define NB 8
#define NPIX 65536
#define CAP1 8192
#define EPS2 8.0f    // exclusion slack: 2x bf16 conv error bound (obs ~0.3)

// monotone float<->uint order-preserving encoding
__device__ __forceinline__ u32 fsort(float f){
  u32 u = __float_as_uint(f);
  return (u & 0x80000000u) ? ~u : (u | 0x80000000u);
}
__device__ __forceinline__ float funsort(u32 s){
  u32 u = (s & 0x80000000u) ? (s ^ 0x80000000u) : ~s;
  return __uint_as_float(u);
}
// round-to-nearest-even f32 -> bf16 bits
__device__ __forceinline__ u32 rneb(float f){
  u32 x = __float_as_uint(f);
  return (x + 0x7fffu + ((x >> 16) & 1u)) >> 16;
}
__device__ __forceinline__ float bf2f(u32 h){ return __uint_as_float(h << 16); }

// ---------------- K1: LDS-tiled transpose filt[d][e] -> filtT[e][d] ---------
__global__ __launch_bounds__(256) void transpose_kernel(
    const float* __restrict__ filt, float* __restrict__ filtT,
    u32* __restrict__ ncand)
{
  __shared__ float T[64][65];
  const int b = blockIdx.x;            // 0..17
  const int e0 = b * 64;
  const int ecnt = min(64, 1089 - e0);
  const int w = threadIdx.x >> 6, l = threadIdx.x & 63;
  if (b == 0 && threadIdx.x < 8) ncand[threadIdx.x] = 0u;
  for (int d = w; d < 64; d += 4)
    if (l < ecnt) T[d][l] = filt[d * 1089 + e0 + l];
  __syncthreads();
  for (int r = w; r < ecnt; r += 4)
    filtT[(e0 + r) * 64 + l] = T[l][r];
}

// ---------------- K2: fragment prep (filt L3-warm; filtT L2-warm) -----------
__global__ __launch_bounds__(256) void prep_kernel(
    const float* __restrict__ filt, const float* __restrict__ filtT,
    const float* __restrict__ prior,
    ushort_t* __restrict__ afh, ushort_t* __restrict__ acolh,
    float* __restrict__ fcorner, float* __restrict__ priorR,
    float* __restrict__ filtT4, float* __restrict__ filtC)
{
  int t = blockIdx.x * 256 + threadIdx.x;   // 16384 threads
  for (int i = t; i < 67584; i += 16384){
    int j = i & 7; int fidx = i >> 3; int lane = fidx & 63; int rest = fidx >> 6;
    int dt = rest & 1; int kc = (rest >> 1) & 1; int fy = rest >> 2;
    int d = dt * 32 + (lane & 31);
    int fx = 16 * kc + 8 * (lane >> 5) + j;
    afh[i] = (ushort_t)rneb(filt[d * 1089 + fy * 33 + fx]);
  }
  for (int i = t; i < 2048; i += 16384){
    int j = i & 7; int fidx = i >> 3; int lane = fidx & 63; int rest = fidx >> 6;
    int dt = rest & 1; int kc = rest >> 1;
    int d = dt * 32 + (lane & 31);
    int fy = 16 * kc + 8 * (lane >> 5) + j;
    acolh[i] = (ushort_t)rneb(filt[d * 1089 + fy * 33 + 32]);
  }
  for (int i = t; i < 2048; i += 16384){
    int reg = i & 15; int rest = i >> 4; int lane = rest & 63; int dt = rest >> 6;
    int d = dt * 32 + (reg & 3) + 8 * (reg >> 2) + 4 * (lane >> 5);
    fcorner[i] = filt[d * 1089 + 1088];
    priorR[i] = prior[d];
  }
  for (int i = t; i < 67584; i += 16384){   // filtT4 from filtT (coalesced)
    int e = i & 3; int d = (i >> 2) & 63; int q = (i >> 8) & 7; int fy = i >> 11;
    filtT4[i] = filtT[(fy * 33 + 4 * q + e) * 64 + d];
  }
  for (int i = t; i < 2112; i += 16384){    // filtC from filtT (coalesced)
    int d = i & 63; int fy = i >> 6;
    filtC[i] = filtT[(fy * 33 + 32) * 64 + d];
  }
}

// ---------------- conv via MFMA (pure bf16 + exact rerank downstream) -------
__device__ __forceinline__ u32 funnel(u32 hi, u32 lo, int sh){
  return (u32)((((u64)hi << 32) | (u64)lo) >> sh);
}
template<int J>
__device__ __forceinline__ short8 extractf(uint4 P0, uint4 P1, int sh){
  u32 W[8] = {P0.x, P0.y, P0.z, P0.w, P1.x, P1.y, P1.z, P1.w};
  uint4 t;
  t.x = funnel(W[J + 1], W[J + 0], sh);
  t.y = funnel(W[J + 2], W[J + 1], sh);
  t.z = funnel(W[J + 3], W[J + 2], sh);
  t.w = funnel(W[J + 4], W[J + 3], sh);
  return __builtin_bit_cast(short8, t);
}
__device__ __forceinline__ f32x16 zero16(){
  f32x16 v;
  #pragma unroll
  for (int i = 0; i < 16; ++i) v[i] = 0.f;
  return v;
}

// LDS: hi rows [36][256] bf16, row stride 512B. Block = 4-row x 256-col stripe.
// Rolling 2-row raw-uint4 register window (parity slots, static idx).
// KEEP EXACT: R11's cross-loop live km + setprio spilled (conv 82->116us).
template<int J>
__device__ __forceinline__ void conv_body(
    const char* ldsc, const ushort_t* lds16, int w, int l, int tX,
    const short8* __restrict__ afh8, const short8* __restrict__ acol8,
    const f32x4* __restrict__ fcp, const f32x4* __restrict__ prp,
    u64* __restrict__ pb, int sh)
{
  const int c = l & 31, h = l >> 5;
  const int y0 = w;                 // 0..7; pixels y = y0 + 8c
  int cob0[2], cob1[2];
  #pragma unroll
  for (int kc = 0; kc < 2; ++kc){
    int yp = (y0 + 8 * c + 16 * kc + 8 * h - 16) & 255;
    int b0 = yp >> 3, b1 = (b0 + 1) & 31;
    cob0[kc] = b0 * 16; cob1[kc] = b1 * 16;
  }
  const int cc = (y0 + 8 * c + 16) & 255;   // column-pass / corner col

#define LA(DST, FY)                                                           \
  { _Pragma("unroll")                                                         \
    for (int kc = 0; kc < 2; ++kc)                                            \
      _Pragma("unroll")                                                       \
      for (int dt = 0; dt < 2; ++dt)                                          \
        DST[kc][dt] = afh8[(((FY) * 2 + kc) * 2 + dt) * 64 + l]; }

#define LW(S, ROWI)                                                           \
  { const char* rb_ = ldsc + (ROWI) * 512;                                    \
    s##S##k0p0 = *(const uint4*)(rb_ + cob0[0]);                              \
    s##S##k0p1 = *(const uint4*)(rb_ + cob1[0]);                              \
    s##S##k1p0 = *(const uint4*)(rb_ + cob0[1]);                              \
    s##S##k1p1 = *(const uint4*)(rb_ + cob1[1]); }

#define CPH(SA, SB, ACUR, ANXT, FYP, DOPF)                                    \
  { if (DOPF){ LA(ANXT, FYP) }                                                \
    short8 b0k0 = extractf<J>(s##SA##k0p0, s##SA##k0p1, sh);                  \
    short8 b0k1 = extractf<J>(s##SA##k1p0, s##SA##k1p1, sh);                  \
    short8 b1k0 = extractf<J>(s##SB##k0p0, s##SB##k0p1, sh);                  \
    short8 b1k1 = extractf<J>(s##SB##k1p0, s##SB##k1p1, sh);                  \
    acc[0][0] = __builtin_amdgcn_mfma_f32_32x32x16_bf16(ACUR[0][0], b0k0, acc[0][0], 0, 0, 0); \
    acc[0][0] = __builtin_amdgcn_mfma_f32_32x32x16_bf16(ACUR[1][0], b0k1, acc[0][0], 0, 0, 0); \
    acc[0][1] = __builtin_amdgcn_mfma_f32_32x32x16_bf16(ACUR[0][1], b0k0, acc[0][1], 0, 0, 0); \
    acc[0][1] = __builtin_amdgcn_mfma_f32_32x32x16_bf16(ACUR[1][1], b0k1, acc[0][1], 0, 0, 0); \
    acc[1][0] = __builtin_amdgcn_mfma_f32_32x32x16_bf16(ACUR[0][0], b1k0, acc[1][0], 0, 0, 0); \
    acc[1][0] = __builtin_amdgcn_mfma_f32_32x32x16_bf16(ACUR[1][0], b1k1, acc[1][0], 0, 0, 0); \
    acc[1][1] = __builtin_amdgcn_mfma_f32_32x32x16_bf16(ACUR[0][1], b1k0, acc[1][1], 0, 0, 0); \
    acc[1][1] = __builtin_amdgcn_mfma_f32_32x32x16_bf16(ACUR[1][1], b1k1, acc[1][1], 0, 0, 0); }

  for (int g0 = 0; g0 < 2; ++g0){
    const int r0 = g0 * 2;                  // output rows r0, r0+1
    f32x16 acc[2][2];                       // [nr][dt]
    #pragma unroll
    for (int nr = 0; nr < 2; ++nr)
      #pragma unroll
      for (int dt = 0; dt < 2; ++dt) acc[nr][dt] = zero16();

    uint4 s0k0p0, s0k0p1, s0k1p0, s0k1p1;   // window slot 0 (even fy row)
    uint4 s1k0p0, s1k0p1, s1k1p0, s1k1p1;   // window slot 1 (odd fy row)
    short8 aA[2][2], aB[2][2];              // A-frag double buffer [kc][dt]

    LW(0, r0)
    LW(1, r0 + 1)
    LA(aA, 0)

    #pragma unroll 1
    for (int fy2 = 0; fy2 < 32; fy2 += 2){
      CPH(0, 1, aA, aB, fy2 + 1, true)      // fy = fy2   (rows fy2, fy2+1)
      LW(0, r0 + fy2 + 2)
      CPH(1, 0, aB, aA, fy2 + 2, true)      // fy = fy2+1 (rows fy2+1, fy2+2)
      LW(1, r0 + fy2 + 3)
    }
    CPH(0, 1, aA, aB, 0, false)             // fy = 32 (rows 32, 33)

    // column pass: fx = 32, k = fy (0..31)
    #pragma unroll
    for (int nr = 0; nr < 2; ++nr){
      #pragma unroll
      for (int kc = 0; kc < 2; ++kc){
        int base = (r0 + nr + 16 * kc + 8 * h) * 512 + cc * 2;
        u32 v0 = *(const ushort_t*)(ldsc + base + 0 * 512);
        u32 v1 = *(const ushort_t*)(ldsc + base + 1 * 512);
        u32 v2 = *(const ushort_t*)(ldsc + base + 2 * 512);
        u32 v3 = *(const ushort_t*)(ldsc + base + 3 * 512);
        u32 v4 = *(const ushort_t*)(ldsc + base + 4 * 512);
        u32 v5 = *(const ushort_t*)(ldsc + base + 5 * 512);
        u32 v6 = *(const ushort_t*)(ldsc + base + 6 * 512);
        u32 v7 = *(const ushort_t*)(ldsc + base + 7 * 512);
        uint4 t;
        t.x = v0 | (v1 << 16); t.y = v2 | (v3 << 16);
        t.z = v4 | (v5 << 16); t.w = v6 | (v7 << 16);
        short8 Bc = __builtin_bit_cast(short8, t);
        #pragma unroll
        for (int dt = 0; dt < 2; ++dt)
          acc[nr][dt] = __builtin_amdgcn_mfma_f32_32x32x16_bf16(
              acol8[(kc * 2 + dt) * 64 + l], Bc, acc[nr][dt], 0, 0, 0);
      }
    }

    // corner (fy=32, fx=32) + prior-scale + per-pixel best + store.
    #pragma unroll
    for (int nr = 0; nr < 2; ++nr){
      float cv = bf2f((u32)lds16[(r0 + nr + 32) * 256 + cc]);
      float bv = -3e38f; int bd = 0;
      #pragma unroll
      for (int dt = 0; dt < 2; ++dt){
        #pragma unroll
        for (int q = 0; q < 4; ++q){
          f32x4 fc4 = fcp[(dt * 64 + l) * 4 + q];
          f32x4 pr4 = prp[(dt * 64 + l) * 4 + q];
          #pragma unroll
          for (int e = 0; e < 4; ++e){
            int reg = q * 4 + e;
            float s = (acc[nr][dt][reg] + fc4[e] * cv) * pr4[e];
            int d = dt * 32 + e + 8 * q + 4 * h;
            if (s > bv || (s == bv && d < bd)){ bv = s; bd = d; }
          }
        }
      }
      int x = tX + r0 + nr;
      int y = y0 + 8 * c;
      u64 key = ((u64)fsort(bv) << 32) | (u64)(63 - bd);
      u64 other = __shfl_xor(key, 32);
      if (other > key) key = other;
      if (h == 0) pb[(x << 8) | y] = key;
    }
  }
#undef CPH
#undef LW
#undef LA
}

__global__ __launch_bounds__(512) void conv_mfma(
    const float* __restrict__ input,
    const ushort_t* __restrict__ afh, const ushort_t* __restrict__ acolh,
    const float* __restrict__ fcorner, const float* __restrict__ priorR,
    u64* __restrict__ packed)
{
  __shared__ ushort_t lds[9216];           // hi [36][256] bf16, 18 KB
  const int bS = blockIdx.x;               // stripe 0..63
  const int b  = blockIdx.y;
  const int tX = bS * 4;
  const int tid = threadIdx.x;

  const float* inb = input + b * NPIX;
  for (int k = tid; k < 1152; k += 512){   // 36 rows * 32 units
    int r = k >> 5, u = k & 31;
    int gx = (tX - 16 + r) & 255;
    const float* src = inb + (gx << 8) + (u << 3);
    float4 v1 = *(const float4*)(src);
    float4 v2 = *(const float4*)(src + 4);
    uint4 t;
    t.x = rneb(v1.x) | (rneb(v1.y) << 16);
    t.y = rneb(v1.z) | (rneb(v1.w) << 16);
    t.z = rneb(v2.x) | (rneb(v2.y) << 16);
    t.w = rneb(v2.z) | (rneb(v2.w) << 16);
    *(uint4*)((char*)lds + r * 512 + u * 16) = t;
  }
  __syncthreads();

  const int w = tid >> 6, l = tid & 63;
  u64* pb = packed + b * NPIX;
  const int sh = 16 * (w & 1);
  const char* ldsc = (const char*)lds;
  const short8* afh8 = (const short8*)afh;
  const short8* acol8 = (const short8*)acolh;
  const f32x4* fcp = (const f32x4*)fcorner;
  const f32x4* prp = (const f32x4*)priorR;

  switch ((w >> 1) & 3){
    case 0: conv_body<0>(ldsc, lds, w, l, tX, afh8, acol8, fcp, prp, pb, sh); break;
    case 1: conv_body<1>(ldsc, lds, w, l, tX, afh8, acol8, fcp, prp, pb, sh); break;
    case 2: conv_body<2>(ldsc, lds, w, l, tX, afh8, acol8, fcp, prp, pb, sh); break;
    default: conv_body<3>(ldsc, lds, w, l, tX, afh8, acol8, fcp, prp, pb, sh); break;
  }
}

// ---------------- lattice lower bound on the 10th pick ----------------------
// 16 sub-cells 16x16 at 64-stride (+24 offset): mutual distance >= 48 > disc
// diameter 47.09 (tmap<1.0f iff d<=23.54) -> each pick touches <= 1 sub-cell
// -> running max at iter t<=9 >= (t+1)-th largest sub-cell max >= L.
// thr[b] = L_approx - EPS2 (covers bf16 error both ways).
__global__ __launch_bounds__(256) void lbound_kernel(
    const u64* __restrict__ packed, float* __restrict__ thr)
{
  const int b = blockIdx.x;
  const int tid = threadIdx.x;
  const u32* ph = (const u32*)(packed + b * NPIX);
  __shared__ u32 red[256];
  __shared__ u32 q16[16];
  const int r = tid >> 4, cY = tid & 15;
  for (int sc = 0; sc < 16; ++sc){
    int x = 24 + ((sc >> 2) << 6) + r;
    int y = 24 + ((sc & 3) << 6) + cY;
    red[tid] = ph[2 * ((x << 8) | y) + 1];
    __syncthreads();
    for (int s = 128; s > 0; s >>= 1){
      if (tid < s) red[tid] = max(red[tid], red[tid + s]);
      __syncthreads();
    }
    if (tid == 0) q16[sc] = red[0];
    __syncthreads();
  }
  if (tid == 0){
    u32 q[16];
    for (int i = 0; i < 16; ++i) q[i] = q16[i];
    u32 tenth = 0;                       // 10 rounds of find-max-and-remove
    for (int k = 0; k < 10; ++k){
      int bi = 0;
      for (int i = 1; i < 16; ++i) if (q[i] > q[bi]) bi = i;
      tenth = q[bi];
      q[bi] = 0;
    }
    thr[b] = funsort(tenth) - EPS2;
  }
}

// ---------------- collect: approx >= thr, interior, per-batch lists ----------
__global__ __launch_bounds__(256) void collect_kernel(const u64* __restrict__ packed,
    const float* __restrict__ thr, u32* __restrict__ ncand, u32* __restrict__ cand){
  const int b = blockIdx.y, blk = blockIdx.x, tid = threadIdx.x;
  u32 tu = fsort(thr[b]);
  const u32* ph = (const u32*)(packed + b * NPIX);
  for (int k = tid; k < 2048; k += 256){
    int p = blk * 2048 + k;
    int px = p >> 8, py = p & 255;
    u32 v = ph[2 * p + 1];
    if (v >= tu && px >= 16 && px < 240 && py >= 16 && py < 240){
      u32 slot = atomicAdd(&ncand[b], 1u);
      if (slot < CAP1) cand[b * CAP1 + slot] = (u32)p;
    }
  }
}

// ---------------- exact fp32 recompute, 4 candidates per wave ----------------
// R19: each wave processes 4 candidates at once -> one filtT4 float4 load
// feeds 16 FMAs (was 4), cutting the 270KB-per-candidate L2 filter stream 4x
// (R18's 90us rerank was L2-BW bound at VALUBusy 9%). Input taps are
// wave-uniform broadcast loads (1 line each). Candidates are interior
// (collect guarantees) -> rows px-16..px+16 in [0,255], no wrap.
__global__ __launch_bounds__(256) void rerank_kernel(
    const float* __restrict__ input, const float* __restrict__ filtT4,
    const float* __restrict__ filtC, const float* __restrict__ prior,
    const u32* __restrict__ ncand, const u32* __restrict__ cand,
    u64* __restrict__ packed)
{
  const int lane = threadIdx.x & 63;       // = d
  const int b = blockIdx.y;
  const int ws = blockIdx.x * 4 + (threadIdx.x >> 6);   // 0..511
  int n = (int)min(ncand[b], (u32)CAP1);
  float pv = prior[lane];
  const float* inb = input + b * NPIX;

  for (int i0 = ws * 4; i0 < n; i0 += 2048){
    int pA = (int)cand[b * CAP1 + i0];
    int pB = (i0 + 1 < n) ? (int)cand[b * CAP1 + i0 + 1] : pA;
    int pC = (i0 + 2 < n) ? (int)cand[b * CAP1 + i0 + 2] : pA;
    int pD = (i0 + 3 < n) ? (int)cand[b * CAP1 + i0 + 3] : pA;
    const float* bA = inb + (((pA >> 8) - 16) << 8) + (pA & 255) - 16;
    const float* bB = inb + (((pB >> 8) - 16) << 8) + (pB & 255) - 16;
    const float* bC = inb + (((pC >> 8) - 16) << 8) + (pC & 255) - 16;
    const float* bD = inb + (((pD >> 8) - 16) << 8) + (pD & 255) - 16;

    float aA0 = 0.f, aA1 = 0.f, aB0 = 0.f, aB1 = 0.f;
    float aC0 = 0.f, aC1 = 0.f, aD0 = 0.f, aD1 = 0.f;
    for (int fy = 0; fy < 33; ++fy){
      const float* irA = bA + (fy << 8);
      const float* irB = bB + (fy << 8);
      const float* irC = bC + (fy << 8);
      const float* irD = bD + (fy << 8);
      const float* ft = filtT4 + fy * 2048 + lane * 4;
      #pragma unroll
      for (int q = 0; q < 8; ++q){
        const float4 fv = *(const float4*)(ft + q * 256);
        aA0 = fmaf(fv.x, irA[4*q+0], aA0); aA1 = fmaf(fv.y, irA[4*q+1], aA1);
        aA0 = fmaf(fv.z, irA[4*q+2], aA0); aA1 = fmaf(fv.w, irA[4*q+3], aA1);
        aB0 = fmaf(fv.x, irB[4*q+0], aB0); aB1 = fmaf(fv.y, irB[4*q+1], aB1);
        aB0 = fmaf(fv.z, irB[4*q+2], aB0); aB1 = fmaf(fv.w, irB[4*q+3], aB1);
        aC0 = fmaf(fv.x, irC[4*q+0], aC0); aC1 = fmaf(fv.y, irC[4*q+1], aC1);
        aC0 = fmaf(fv.z, irC[4*q+2], aC0); aC1 = fmaf(fv.w, irC[4*q+3], aC1);
        aD0 = fmaf(fv.x, irD[4*q+0], aD0); aD1 = fmaf(fv.y, irD[4*q+1], aD1);
        aD0 = fmaf(fv.z, irD[4*q+2], aD0); aD1 = fmaf(fv.w, irD[4*q+3], aD1);
      }
      const float fc = filtC[fy * 64 + lane];
      aA0 = fmaf(fc, irA[32], aA0);
      aB0 = fmaf(fc, irB[32], aB0);
      aC0 = fmaf(fc, irC[32], aC0);
      aD0 = fmaf(fc, irD[32], aD0);
    }

#define EMIT(P, S, VALID)                                                     \
    {                                                                         \
      u64 key = ((u64)fsort((S) * pv) << 32) | (u64)(63 - lane);              \
      _Pragma("unroll")                                                       \
      for (int off = 32; off; off >>= 1){                                     \
        u64 o = __shfl_down(key, off);                                        \
        if (o > key) key = o;                                                 \
      }                                                                       \
      if (lane == 0 && (VALID)) packed[b * NPIX + (P)] = key;                 \
    }
    EMIT(pA, aA0 + aA1, true)
    EMIT(pB, aB0 + aB1, i0 + 1 < n)
    EMIT(pC, aC0 + aC1, i0 + 2 < n)
    EMIT(pD, aD0 + aD1, i0 + 3 < n)
#undef EMIT
  }
}

// ---------------- greedy on shortlist (exact) --------------------------------
// Sound by the lattice bound: excluded pixels have exact value < thr+EPS2 =
// L_approx <= ... < every iteration's running max. Fallback (full map,
// partially patched) only on CAP overflow.
__global__ __launch_bounds__(1024) void greedy_sl(
    const u64* __restrict__ packed, const float* __restrict__ prior,
    const u32* __restrict__ ncand, const u32* __restrict__ cand,
    float* __restrict__ out)
{
  const int b = blockIdx.x;
  const int tid = threadIdx.x;
  const u64* pb = packed + b * NPIX;
  const int n = (int)min(ncand[b], (u32)CAP1);

  int cp[8]; float cv[8];
  #pragma unroll
  for (int k = 0; k < 8; ++k){
    int idx = tid + k * 1024;
    if (idx < n){ cp[k] = (int)cand[b * CAP1 + idx]; cv[k] = funsort((u32)(pb[cp[k]] >> 32)); }
    else        { cp[k] = 0; cv[k] = -3e38f; }
  }

  __shared__ u64 warr[16];
  __shared__ int spx, spy, okf;
  if (tid == 0){ spx = -100000; spy = -100000; okf = (ncand[b] <= (u32)CAP1); }
  __syncthreads();
  if (okf){
    for (int t = 0; t < 10; ++t){
      const int px = spx, py = spy;
      if (px >= 0){
        #pragma unroll
        for (int k = 0; k < 8; ++k){
          if (tid + k * 1024 < n){
            float dx = (float)((cp[k] >> 8) - px), dy = (float)((cp[k] & 255) - py);
            float d2 = dx * dx + dy * dy;
            float tmap = 1.f - __expf(d2 * -0.03125f);
            if (d2 <= 16.f) tmap = 0.f;
            cv[k] *= tmap;
          }
        }
      }
      u64 key = 0ull;
      #pragma unroll
      for (int k = 0; k < 8; ++k){
        u64 kk = ((u64)fsort(cv[k]) << 32) | (u64)(0xFFFFu ^ (u32)cp[k]);
        if (kk > key) key = kk;
      }
      #pragma unroll
      for (int off = 32; off; off >>= 1){
        u64 o = __shfl_down(key, off);
        if (o > key) key = o;
      }
      if ((tid & 63) == 0) warr[tid >> 6] = key;
      __syncthreads();
      if (tid < 64){
        u64 k2 = (tid < 16) ? warr[tid] : 0ull;
        #pragma unroll
        for (int off = 8; off; off >>= 1){
          u64 o = __shfl_down(k2, off);
          if (o > k2) k2 = o;
        }
        if (tid == 0){
          int id = 0xFFFF ^ (int)(k2 & 0xFFFFull);
          float v = funsort((u32)(k2 >> 32));
          u64 pk = pb[id];
          int d = 63 - (int)(pk & 63ull);
          float bvv = funsort((u32)(pk >> 32));
          int xx = id >> 8, yy = id & 255;
          out[b * 30 + t * 3 + 0] = (float)d;
          out[b * 30 + t * 3 + 1] = (float)xx;
          out[b * 30 + t * 3 + 2] = (float)yy;
          out[240 + b * 20 + t * 2 + 0] = v;              // ov0 (umax==1 exact)
          out[240 + b * 20 + t * 2 + 1] = bvv / prior[d]; // ov1
          spx = xx; spy = yy;
        }
      }
      __syncthreads();
    }
    return;
  }

  { // CAP-overflow fallback: full-map greedy on (partially patched) map
    const int x = tid >> 2;
    const int ybase = (tid & 3) << 6;
    const int pbase = (x << 8) + ybase;
    float s[64];
    const bool rowin = (x >= 16 && x < 240);
    #pragma unroll
    for (int i2 = 0; i2 < 32; ++i2){
      uint4 two = *(const uint4*)(pb + pbase + 2 * i2);
      int y = ybase + 2 * i2;
      s[2*i2+0] = (rowin && y+0 >= 16 && y+0 < 240) ? funsort(two.y) : 0.0f;
      s[2*i2+1] = (rowin && y+1 >= 16 && y+1 < 240) ? funsort(two.w) : 0.0f;
    }
    float tm = -3e38f; int tp = pbase;
    #pragma unroll
    for (int i = 0; i < 64; ++i){
      if (s[i] > tm){ tm = s[i]; tp = pbase + i; }
    }
    __syncthreads();
    for (int t = 0; t < 10; ++t){
      const int px = spx, py = spy;
      if (px >= 0){
        int dxr = x - px;
        if (dxr >= -24 && dxr <= 24){
          int lo = py - 24 - ybase;
          int hi = py + 24 - ybase;
          if (lo < 64 && hi >= 0){
            float dx2 = (float)(dxr * dxr);
            tm = -3e38f; tp = pbase;
            #pragma unroll
            for (int i = 0; i < 64; ++i){
              if (i >= lo && i <= hi){
                float dy = (float)(ybase + i - py);
                float d2 = dx2 + dy * dy;
                float tmap = 1.f - __expf(d2 * -0.03125f);
                if (d2 <= 16.f) tmap = 0.f;
                s[i] *= tmap;
              }
              if (s[i] > tm){ tm = s[i]; tp = pbase + i; }
            }
          }
        }
      }
      u64 key = ((u64)fsort(tm) << 32) | (u64)(0xFFFFu ^ (u32)tp);
      #pragma unroll
      for (int off = 32; off; off >>= 1){
        u64 o = __shfl_down(key, off);
        if (o > key) key = o;
      }
      if ((tid & 63) == 0) warr[tid >> 6] = key;
      __syncthreads();
      if (tid < 64){
        u64 k2 = (tid < 16) ? warr[tid] : 0ull;
        #pragma unroll
        for (int off = 8; off; off >>= 1){
          u64 o = __shfl_down(k2, off);
          if (o > k2) k2 = o;
        }
        if (tid == 0){
          int id = 0xFFFF ^ (int)(k2 & 0xFFFFull);
          float v = funsort((u32)(k2 >> 32));
          u64 pk = pb[id];
          int d = 63 - (int)(pk & 63ull);
          float bvv = funsort((u32)(pk >> 32));
          int xx = id >> 8, yy = id & 255;
          out[b * 30 + t * 3 + 0] = (float)d;
          out[b * 30 + t * 3 + 1] = (float)xx;
          out[b * 30 + t * 3 + 2] = (float)yy;
          out[240 + b * 20 + t * 2 + 0] = v;
          out[240 + b * 20 + t * 2 + 1] = bvv / prior[d];
          spx = xx; spy = yy;
        }
      }
      __syncthreads();
    }
  }
}

extern "C" void kernel_launch(void* const* d_in, const int* in_sizes, int n_in,
                              void* d_out, int out_size, void* d_ws, size_t ws_size,
                              hipStream_t stream)
{
  const float* input = (const float*)d_in[0];
  const float* filt  = (const float*)d_in[1];
  const float* prior = (const float*)d_in[3];
  float* out = (float*)d_out;

  char* ws = (char*)d_ws;
  u64*      packed  = (u64*)(ws);                    // 4,194,304
  u32*      ncand   = (u32*)  (ws + 4194304);        // 64 B
  float*    thr     = (float*)(ws + 4194368);        // 64 B
  ushort_t* afh     = (ushort_t*)(ws + 4194432);     // 135,168
  ushort_t* acolh   = (ushort_t*)(ws + 4329600);     // 4,096
  float*    fcorner = (float*)(ws + 4333696);        // 8,192
  float*    priorR  = (float*)(ws + 4341888);        // 8,192
  u32*      cand    = (u32*)  (ws + 4350080);        // 8*8192*4 = 262,144
  float*    filtT4  = (float*)(ws + 4612224);        // 270,336
  float*    filtC   = (float*)(ws + 4882560);        // 8,448
  float*    filtT   = (float*)(ws + 4891008);        // 278,784 -> 5,169,792

  transpose_kernel<<<18, 256, 0, stream>>>(filt, filtT, ncand);
  prep_kernel<<<64, 256, 0, stream>>>(filt, filtT, prior, afh, acolh,
                                      fcorner, priorR, filtT4, filtC);
  conv_mfma<<<dim3(64, NB), 512, 0, stream>>>(input, afh, acolh, fcorner, priorR, packed);
  lbound_kernel<<<NB, 256, 0, stream>>>(packed, thr);
  collect_kernel<<<dim3(32, NB), 256, 0, stream>>>(packed, thr, ncand, cand);
  rerank_kernel<<<dim3(128, NB), 256, 0, stream>>>(input, filtT4, filtC, prior,
                                                   ncand, cand, packed);
  greedy_sl<<<NB, 1024, 0, stream>>>(packed, prior, ncand, cand, out);
}

// Round 20
// 264.273 us; speedup vs baseline: 1.2283x; 1.2283x over previous
//
#include <hip/hip_runtime.h>

typedef unsigned long long u64;
typedef unsigned int u32;
typedef unsigned short ushort_t;

using f32x16 = __attribute__((ext_vector_type(16))) float;
using f32x4  = __attribute__((ext_vector_type(4))) float;
using short8 = __attribute__((ext_vector_type(8))) short;

#define NB 8
#define NPIX 65536
#define CAP1 8192
#define CAP2 4096
#define T1    24.0f   // pregreedy shortlist band below approx max
#define SLACK 12.0f   // exact-rerank band below v10 (R15/R16-proven)
#define CERTF 10.0f   // final cert: v10_final >= tmin - 10 (excluded < tmin-11.4)

// monotone float<->uint order-preserving encoding
__device__ __forceinline__ u32 fsort(float f){
  u32 u = __float_as_uint(f);
  return (u & 0x80000000u) ? ~u : (u | 0x80000000u);
}
__device__ __forceinline__ float funsort(u32 s){
  u32 u = (s & 0x80000000u) ? (s ^ 0x80000000u) : ~s;
  return __uint_as_float(u);
}
// round-to-nearest-even f32 -> bf16 bits
__device__ __forceinline__ u32 rneb(float f){
  u32 x = __float_as_uint(f);
  return (x + 0x7fffu + ((x >> 16) & 1u)) >> 16;
}
__device__ __forceinline__ float bf2f(u32 h){ return __uint_as_float(h << 16); }

// ---------------- K1: LDS-tiled transpose filt[d][e] -> filtT[e][d] ---------
__global__ __launch_bounds__(256) void transpose_kernel(
    const float* __restrict__ filt, float* __restrict__ filtT,
    u32* __restrict__ nc16, u32* __restrict__ mmax)
{
  __shared__ float T[64][65];
  const int b = blockIdx.x;            // 0..17
  const int e0 = b * 64;
  const int ecnt = min(64, 1089 - e0);
  const int w = threadIdx.x >> 6, l = threadIdx.x & 63;
  if (b == 0 && threadIdx.x < 16) nc16[threadIdx.x] = 0u;
  if (b == 0 && threadIdx.x < 8)  mmax[threadIdx.x] = 0u;
  for (int d = w; d < 64; d += 4)
    if (l < ecnt) T[d][l] = filt[d * 1089 + e0 + l];
  __syncthreads();
  for (int r = w; r < ecnt; r += 4)
    filtT[(e0 + r) * 64 + l] = T[l][r];
}

// ---------------- K2: fragment prep (filt L3-warm; filtT L2-warm) -----------
__global__ __launch_bounds__(256) void prep_kernel(
    const float* __restrict__ filt, const float* __restrict__ filtT,
    const float* __restrict__ prior,
    ushort_t* __restrict__ afh, ushort_t* __restrict__ acolh,
    float* __restrict__ fcorner, float* __restrict__ priorR,
    float* __restrict__ filtT4, float* __restrict__ filtC)
{
  int t = blockIdx.x * 256 + threadIdx.x;   // 16384 threads
  for (int i = t; i < 67584; i += 16384){
    int j = i & 7; int fidx = i >> 3; int lane = fidx & 63; int rest = fidx >> 6;
    int dt = rest & 1; int kc = (rest >> 1) & 1; int fy = rest >> 2;
    int d = dt * 32 + (lane & 31);
    int fx = 16 * kc + 8 * (lane >> 5) + j;
    afh[i] = (ushort_t)rneb(filt[d * 1089 + fy * 33 + fx]);
  }
  for (int i = t; i < 2048; i += 16384){
    int j = i & 7; int fidx = i >> 3; int lane = fidx & 63; int rest = fidx >> 6;
    int dt = rest & 1; int kc = rest >> 1;
    int d = dt * 32 + (lane & 31);
    int fy = 16 * kc + 8 * (lane >> 5) + j;
    acolh[i] = (ushort_t)rneb(filt[d * 1089 + fy * 33 + 32]);
  }
  for (int i = t; i < 2048; i += 16384){
    int reg = i & 15; int rest = i >> 4; int lane = rest & 63; int dt = rest >> 6;
    int d = dt * 32 + (reg & 3) + 8 * (reg >> 2) + 4 * (lane >> 5);
    fcorner[i] = filt[d * 1089 + 1088];
    priorR[i] = prior[d];
  }
  for (int i = t; i < 67584; i += 16384){   // filtT4 from filtT (coalesced)
    int e = i & 3; int d = (i >> 2) & 63; int q = (i >> 8) & 7; int fy = i >> 11;
    filtT4[i] = filtT[(fy * 33 + 4 * q + e) * 64 + d];
  }
  for (int i = t; i < 2112; i += 16384){    // filtC from filtT (coalesced)
    int d = i & 63; int fy = i >> 6;
    filtC[i] = filtT[(fy * 33 + 32) * 64 + d];
  }
}

// ---------------- conv via MFMA (pure bf16 + exact rerank downstream) -------
__device__ __forceinline__ u32 funnel(u32 hi, u32 lo, int sh){
  return (u32)((((u64)hi << 32) | (u64)lo) >> sh);
}
template<int J>
__device__ __forceinline__ short8 extractf(uint4 P0, uint4 P1, int sh){
  u32 W[8] = {P0.x, P0.y, P0.z, P0.w, P1.x, P1.y, P1.z, P1.w};
  uint4 t;
  t.x = funnel(W[J + 1], W[J + 0], sh);
  t.y = funnel(W[J + 2], W[J + 1], sh);
  t.z = funnel(W[J + 3], W[J + 2], sh);
  t.w = funnel(W[J + 4], W[J + 3], sh);
  return __builtin_bit_cast(short8, t);
}
__device__ __forceinline__ f32x16 zero16(){
  f32x16 v;
  #pragma unroll
  for (int i = 0; i < 16; ++i) v[i] = 0.f;
  return v;
}

// LDS: hi rows [36][256] bf16, row stride 512B. Block = 4-row x 256-col stripe.
// Rolling 2-row raw-uint4 register window (parity slots, static idx).
// KEEP EXACT: R11's cross-loop live km + setprio spilled (conv 82->116us).
template<int J>
__device__ __forceinline__ void conv_body(
    const char* ldsc, const ushort_t* lds16, int w, int l, int tX,
    const short8* __restrict__ afh8, const short8* __restrict__ acol8,
    const f32x4* __restrict__ fcp, const f32x4* __restrict__ prp,
    u64* __restrict__ pb, int sh)
{
  const int c = l & 31, h = l >> 5;
  const int y0 = w;                 // 0..7; pixels y = y0 + 8c
  int cob0[2], cob1[2];
  #pragma unroll
  for (int kc = 0; kc < 2; ++kc){
    int yp = (y0 + 8 * c + 16 * kc + 8 * h - 16) & 255;
    int b0 = yp >> 3, b1 = (b0 + 1) & 31;
    cob0[kc] = b0 * 16; cob1[kc] = b1 * 16;
  }
  const int cc = (y0 + 8 * c + 16) & 255;   // column-pass / corner col

#define LA(DST, FY)                                                           \
  { _Pragma("unroll")                                                         \
    for (int kc = 0; kc < 2; ++kc)                                            \
      _Pragma("unroll")                                                       \
      for (int dt = 0; dt < 2; ++dt)                                          \
        DST[kc][dt] = afh8[(((FY) * 2 + kc) * 2 + dt) * 64 + l]; }

#define LW(S, ROWI)                                                           \
  { const char* rb_ = ldsc + (ROWI) * 512;                                    \
    s##S##k0p0 = *(const uint4*)(rb_ + cob0[0]);                              \
    s##S##k0p1 = *(const uint4*)(rb_ + cob1[0]);                              \
    s##S##k1p0 = *(const uint4*)(rb_ + cob0[1]);                              \
    s##S##k1p1 = *(const uint4*)(rb_ + cob1[1]); }

#define CPH(SA, SB, ACUR, ANXT, FYP, DOPF)                                    \
  { if (DOPF){ LA(ANXT, FYP) }                                                \
    short8 b0k0 = extractf<J>(s##SA##k0p0, s##SA##k0p1, sh);                  \
    short8 b0k1 = extractf<J>(s##SA##k1p0, s##SA##k1p1, sh);                  \
    short8 b1k0 = extractf<J>(s##SB##k0p0, s##SB##k0p1, sh);                  \
    short8 b1k1 = extractf<J>(s##SB##k1p0, s##SB##k1p1, sh);                  \
    acc[0][0] = __builtin_amdgcn_mfma_f32_32x32x16_bf16(ACUR[0][0], b0k0, acc[0][0], 0, 0, 0); \
    acc[0][0] = __builtin_amdgcn_mfma_f32_32x32x16_bf16(ACUR[1][0], b0k1, acc[0][0], 0, 0, 0); \
    acc[0][1] = __builtin_amdgcn_mfma_f32_32x32x16_bf16(ACUR[0][1], b0k0, acc[0][1], 0, 0, 0); \
    acc[0][1] = __builtin_amdgcn_mfma_f32_32x32x16_bf16(ACUR[1][1], b0k1, acc[0][1], 0, 0, 0); \
    acc[1][0] = __builtin_amdgcn_mfma_f32_32x32x16_bf16(ACUR[0][0], b1k0, acc[1][0], 0, 0, 0); \
    acc[1][0] = __builtin_amdgcn_mfma_f32_32x32x16_bf16(ACUR[1][0], b1k1, acc[1][0], 0, 0, 0); \
    acc[1][1] = __builtin_amdgcn_mfma_f32_32x32x16_bf16(ACUR[0][1], b1k0, acc[1][1], 0, 0, 0); \
    acc[1][1] = __builtin_amdgcn_mfma_f32_32x32x16_bf16(ACUR[1][1], b1k1, acc[1][1], 0, 0, 0); }

  for (int g0 = 0; g0 < 2; ++g0){
    const int r0 = g0 * 2;                  // output rows r0, r0+1
    f32x16 acc[2][2];                       // [nr][dt]
    #pragma unroll
    for (int nr = 0; nr < 2; ++nr)
      #pragma unroll
      for (int dt = 0; dt < 2; ++dt) acc[nr][dt] = zero16();

    uint4 s0k0p0, s0k0p1, s0k1p0, s0k1p1;   // window slot 0 (even fy row)
    uint4 s1k0p0, s1k0p1, s1k1p0, s1k1p1;   // window slot 1 (odd fy row)
    short8 aA[2][2], aB[2][2];              // A-frag double buffer [kc][dt]

    LW(0, r0)
    LW(1, r0 + 1)
    LA(aA, 0)

    #pragma unroll 1
    for (int fy2 = 0; fy2 < 32; fy2 += 2){
      CPH(0, 1, aA, aB, fy2 + 1, true)      // fy = fy2   (rows fy2, fy2+1)
      LW(0, r0 + fy2 + 2)
      CPH(1, 0, aB, aA, fy2 + 2, true)      // fy = fy2+1 (rows fy2+1, fy2+2)
      LW(1, r0 + fy2 + 3)
    }
    CPH(0, 1, aA, aB, 0, false)             // fy = 32 (rows 32, 33)

    // column pass: fx = 32, k = fy (0..31)
    #pragma unroll
    for (int nr = 0; nr < 2; ++nr){
      #pragma unroll
      for (int kc = 0; kc < 2; ++kc){
        int base = (r0 + nr + 16 * kc + 8 * h) * 512 + cc * 2;
        u32 v0 = *(const ushort_t*)(ldsc + base + 0 * 512);
        u32 v1 = *(const ushort_t*)(ldsc + base + 1 * 512);
        u32 v2 = *(const ushort_t*)(ldsc + base + 2 * 512);
        u32 v3 = *(const ushort_t*)(ldsc + base + 3 * 512);
        u32 v4 = *(const ushort_t*)(ldsc + base + 4 * 512);
        u32 v5 = *(const ushort_t*)(ldsc + base + 5 * 512);
        u32 v6 = *(const ushort_t*)(ldsc + base + 6 * 512);
        u32 v7 = *(const ushort_t*)(ldsc + base + 7 * 512);
        uint4 t;
        t.x = v0 | (v1 << 16); t.y = v2 | (v3 << 16);
        t.z = v4 | (v5 << 16); t.w = v6 | (v7 << 16);
        short8 Bc = __builtin_bit_cast(short8, t);
        #pragma unroll
        for (int dt = 0; dt < 2; ++dt)
          acc[nr][dt] = __builtin_amdgcn_mfma_f32_32x32x16_bf16(
              acol8[(kc * 2 + dt) * 64 + l], Bc, acc[nr][dt], 0, 0, 0);
      }
    }

    // corner (fy=32, fx=32) + prior-scale + per-pixel best + store.
    #pragma unroll
    for (int nr = 0; nr < 2; ++nr){
      float cv = bf2f((u32)lds16[(r0 + nr + 32) * 256 + cc]);
      float bv = -3e38f; int bd = 0;
      #pragma unroll
      for (int dt = 0; dt < 2; ++dt){
        #pragma unroll
        for (int q = 0; q < 4; ++q){
          f32x4 fc4 = fcp[(dt * 64 + l) * 4 + q];
          f32x4 pr4 = prp[(dt * 64 + l) * 4 + q];
          #pragma unroll
          for (int e = 0; e < 4; ++e){
            int reg = q * 4 + e;
            float s = (acc[nr][dt][reg] + fc4[e] * cv) * pr4[e];
            int d = dt * 32 + e + 8 * q + 4 * h;
            if (s > bv || (s == bv && d < bd)){ bv = s; bd = d; }
          }
        }
      }
      int x = tX + r0 + nr;
      int y = y0 + 8 * c;
      u64 key = ((u64)fsort(bv) << 32) | (u64)(63 - bd);
      u64 other = __shfl_xor(key, 32);
      if (other > key) key = other;
      if (h == 0) pb[(x << 8) | y] = key;
    }
  }
#undef CPH
#undef LW
#undef LA
}

__global__ __launch_bounds__(512) void conv_mfma(
    const float* __restrict__ input,
    const ushort_t* __restrict__ afh, const ushort_t* __restrict__ acolh,
    const float* __restrict__ fcorner, const float* __restrict__ priorR,
    u64* __restrict__ packed)
{
  __shared__ ushort_t lds[9216];           // hi [36][256] bf16, 18 KB
  const int bS = blockIdx.x;               // stripe 0..63
  const int b  = blockIdx.y;
  const int tX = bS * 4;
  const int tid = threadIdx.x;

  const float* inb = input + b * NPIX;
  for (int k = tid; k < 1152; k += 512){   // 36 rows * 32 units
    int r = k >> 5, u = k & 31;
    int gx = (tX - 16 + r) & 255;
    const float* src = inb + (gx << 8) + (u << 3);
    float4 v1 = *(const float4*)(src);
    float4 v2 = *(const float4*)(src + 4);
    uint4 t;
    t.x = rneb(v1.x) | (rneb(v1.y) << 16);
    t.y = rneb(v1.z) | (rneb(v1.w) << 16);
    t.z = rneb(v2.x) | (rneb(v2.y) << 16);
    t.w = rneb(v2.z) | (rneb(v2.w) << 16);
    *(uint4*)((char*)lds + r * 512 + u * 16) = t;
  }
  __syncthreads();

  const int w = tid >> 6, l = tid & 63;
  u64* pb = packed + b * NPIX;
  const int sh = 16 * (w & 1);
  const char* ldsc = (const char*)lds;
  const short8* afh8 = (const short8*)afh;
  const short8* acol8 = (const short8*)acolh;
  const f32x4* fcp = (const f32x4*)fcorner;
  const f32x4* prp = (const f32x4*)priorR;

  switch ((w >> 1) & 3){
    case 0: conv_body<0>(ldsc, lds, w, l, tX, afh8, acol8, fcp, prp, pb, sh); break;
    case 1: conv_body<1>(ldsc, lds, w, l, tX, afh8, acol8, fcp, prp, pb, sh); break;
    case 2: conv_body<2>(ldsc, lds, w, l, tX, afh8, acol8, fcp, prp, pb, sh); break;
    default: conv_body<3>(ldsc, lds, w, l, tX, afh8, acol8, fcp, prp, pb, sh); break;
  }
}

// ---------------- per-batch approx max ---------------------------------------
__global__ __launch_bounds__(256) void bmax_kernel(const u64* __restrict__ packed,
                                                   u32* __restrict__ mmax){
  const int b = blockIdx.y, blk = blockIdx.x, tid = threadIdx.x;
  const u32* ph = (const u32*)(packed + b * NPIX);
  u32 m = 0;
  for (int k = tid; k < 2048; k += 256) m = max(m, ph[2 * (blk * 2048 + k) + 1]);
  __shared__ u32 red[256];
  red[tid] = m; __syncthreads();
  for (int s = 128; s > 0; s >>= 1){
    if (tid < s) red[tid] = max(red[tid], red[tid + s]);
    __syncthreads();
  }
  if (tid == 0) atomicMax(&mmax[b], red[0]);
}

// ---------------- collect1: approx >= M - T1 (pregreedy shortlist) -----------
__global__ __launch_bounds__(256) void collect1_kernel(const u64* __restrict__ packed,
    const u32* __restrict__ mmax, u32* __restrict__ nc16, u32* __restrict__ cand){
  const int b = blockIdx.y, blk = blockIdx.x, tid = threadIdx.x;
  u32 tu = fsort(funsort(mmax[b]) - T1);
  const u32* ph = (const u32*)(packed + b * NPIX);
  for (int k = tid; k < 2048; k += 256){
    int p = blk * 2048 + k;
    int px = p >> 8, py = p & 255;
    u32 v = ph[2 * p + 1];
    if (v >= tu && px >= 16 && px < 240 && py >= 16 && py < 240){
      u32 slot = atomicAdd(&nc16[b], 1u);
      if (slot < CAP1) cand[b * CAP1 + slot] = (u32)p;
    }
  }
}

// ---------------- pregreedy: approx greedy on S -> tmin[b] = v10 -------------
// Cert: n<=CAP1 && v10 >= M-(T1-1): every excluded pixel has approx < M-T1 <
// every iteration's running max -> S-run == full-map run. Fallback: full map.
__global__ __launch_bounds__(1024) void pregreedy_kernel(
    const u64* __restrict__ packed, const u32* __restrict__ nc16,
    const u32* __restrict__ cand, const u32* __restrict__ mmax,
    float* __restrict__ tmin)
{
  const int b = blockIdx.x;
  const int tid = threadIdx.x;
  const u64* pb = packed + b * NPIX;
  const int n = (int)min(nc16[b], (u32)CAP1);

  int cp[8]; float cv[8];
  #pragma unroll
  for (int k = 0; k < 8; ++k){
    int idx = tid + k * 1024;
    if (idx < n){ cp[k] = (int)cand[b * CAP1 + idx]; cv[k] = funsort((u32)(pb[cp[k]] >> 32)); }
    else        { cp[k] = 0; cv[k] = -3e38f; }
  }

  __shared__ u64 warr[16];
  __shared__ int spx, spy, okf;
  __shared__ float v10s;
  if (tid == 0){ spx = -100000; spy = -100000; }
  __syncthreads();

  for (int t = 0; t < 10; ++t){
    const int px = spx, py = spy;
    if (px >= 0){
      #pragma unroll
      for (int k = 0; k < 8; ++k){
        if (tid + k * 1024 < n){
          float dx = (float)((cp[k] >> 8) - px), dy = (float)((cp[k] & 255) - py);
          float d2 = dx * dx + dy * dy;
          float tmap = 1.f - __expf(d2 * -0.03125f);
          if (d2 <= 16.f) tmap = 0.f;
          cv[k] *= tmap;
        }
      }
    }
    u64 key = 0ull;
    #pragma unroll
    for (int k = 0; k < 8; ++k){
      u64 kk = ((u64)fsort(cv[k]) << 32) | (u64)(0xFFFFu ^ (u32)cp[k]);
      if (kk > key) key = kk;
    }
    #pragma unroll
    for (int off = 32; off; off >>= 1){
      u64 o = __shfl_down(key, off);
      if (o > key) key = o;
    }
    if ((tid & 63) == 0) warr[tid >> 6] = key;
    __syncthreads();
    if (tid < 64){
      u64 k2 = (tid < 16) ? warr[tid] : 0ull;
      #pragma unroll
      for (int off = 8; off; off >>= 1){
        u64 o = __shfl_down(k2, off);
        if (o > k2) k2 = o;
      }
      if (tid == 0){
        int id = 0xFFFF ^ (int)(k2 & 0xFFFFull);
        spx = id >> 8; spy = id & 255;
        if (t == 9) v10s = funsort((u32)(k2 >> 32));
      }
    }
    __syncthreads();
  }

  if (tid == 0)
    okf = (nc16[b] <= (u32)CAP1 && v10s >= funsort(mmax[b]) - (T1 - 1.0f)) ? 1 : 0;
  __syncthreads();
  if (okf){ if (tid == 0) tmin[b] = v10s; return; }

  { // fallback: full-map approx greedy, tmin = its v10
    const int x = tid >> 2;
    const int ybase = (tid & 3) << 6;
    const int pbase = (x << 8) + ybase;
    float s[64];
    const bool rowin = (x >= 16 && x < 240);
    #pragma unroll
    for (int i2 = 0; i2 < 32; ++i2){
      uint4 two = *(const uint4*)(pb + pbase + 2 * i2);
      int y = ybase + 2 * i2;
      s[2*i2+0] = (rowin && y+0 >= 16 && y+0 < 240) ? funsort(two.y) : 0.0f;
      s[2*i2+1] = (rowin && y+1 >= 16 && y+1 < 240) ? funsort(two.w) : 0.0f;
    }
    float tm = -3e38f; int tp = pbase;
    #pragma unroll
    for (int i = 0; i < 64; ++i){
      if (s[i] > tm){ tm = s[i]; tp = pbase + i; }
    }
    if (tid == 0){ spx = -100000; spy = -100000; }
    __syncthreads();
    for (int t = 0; t < 10; ++t){
      const int px = spx, py = spy;
      if (px >= 0){
        int dxr = x - px;
        if (dxr >= -24 && dxr <= 24){
          int lo = py - 24 - ybase;
          int hi = py + 24 - ybase;
          if (lo < 64 && hi >= 0){
            float dx2 = (float)(dxr * dxr);
            tm = -3e38f; tp = pbase;
            #pragma unroll
            for (int i = 0; i < 64; ++i){
              if (i >= lo && i <= hi){
                float dy = (float)(ybase + i - py);
                float d2 = dx2 + dy * dy;
                float tmap = 1.f - __expf(d2 * -0.03125f);
                if (d2 <= 16.f) tmap = 0.f;
                s[i] *= tmap;
              }
              if (s[i] > tm){ tm = s[i]; tp = pbase + i; }
            }
          }
        }
      }
      u64 key = ((u64)fsort(tm) << 32) | (u64)(0xFFFFu ^ (u32)tp);
      #pragma unroll
      for (int off = 32; off; off >>= 1){
        u64 o = __shfl_down(key, off);
        if (o > key) key = o;
      }
      if ((tid & 63) == 0) warr[tid >> 6] = key;
      __syncthreads();
      if (tid < 64){
        u64 k2 = (tid < 16) ? warr[tid] : 0ull;
        #pragma unroll
        for (int off = 8; off; off >>= 1){
          u64 o = __shfl_down(k2, off);
          if (o > k2) k2 = o;
        }
        if (tid == 0){
          int id = 0xFFFF ^ (int)(k2 & 0xFFFFull);
          spx = id >> 8; spy = id & 255;
          if (t == 9) tmin[b] = funsort((u32)(k2 >> 32));
        }
      }
      __syncthreads();
    }
  }
}

// ---------------- collect2: approx >= tmin - SLACK (exact band) --------------
__global__ __launch_bounds__(256) void collect2_kernel(const u64* __restrict__ packed,
    const float* __restrict__ tmin, u32* __restrict__ nc16, u32* __restrict__ cand2){
  const int b = blockIdx.y, blk = blockIdx.x, tid = threadIdx.x;
  u32 tu = fsort(tmin[b] - SLACK);
  const u32* ph = (const u32*)(packed + b * NPIX);
  for (int k = tid; k < 2048; k += 256){
    int p = blk * 2048 + k;
    int px = p >> 8, py = p & 255;
    u32 v = ph[2 * p + 1];
    if (v >= tu && px >= 16 && px < 240 && py >= 16 && py < 240){
      u32 slot = atomicAdd(&nc16[8 + b], 1u);
      if (slot < CAP2) cand2[b * CAP2 + slot] = (u32)p;
    }
  }
}

// ---------------- exact fp32 recompute for C, patch map (R18 structure) ------
__global__ __launch_bounds__(256) void rerank_kernel(
    const float* __restrict__ input, const float* __restrict__ filtT4,
    const float* __restrict__ filtC, const float* __restrict__ prior,
    const u32* __restrict__ nc16, const u32* __restrict__ cand2,
    u64* __restrict__ packed)
{
  const int lane = threadIdx.x & 63;       // = d
  const int b = blockIdx.y;
  const int ws = blockIdx.x * 4 + (threadIdx.x >> 6);   // 0..511
  int n = (int)min(nc16[8 + b], (u32)CAP2);
  float pv = prior[lane];
  for (int i = ws; i < n; i += 512){
    int p = (int)cand2[b * CAP2 + i];
    int px = p >> 8;
    int yc = (p & 255) - 16;
    float s0 = 0.f, s1 = 0.f, s2 = 0.f, s3 = 0.f;
    for (int fy = 0; fy < 33; ++fy){
      const float* ir = input + b * NPIX + ((px + fy - 16) << 8) + yc;
      const float* ft = filtT4 + fy * 2048 + lane * 4;
      #pragma unroll
      for (int q = 0; q < 8; ++q){
        const float4 fv = *(const float4*)(ft + q * 256);
        s0 = fmaf(fv.x, ir[4*q+0], s0);
        s1 = fmaf(fv.y, ir[4*q+1], s1);
        s2 = fmaf(fv.z, ir[4*q+2], s2);
        s3 = fmaf(fv.w, ir[4*q+3], s3);
      }
      s0 = fmaf(filtC[fy * 64 + lane], ir[32], s0);
    }
    float s = (s0 + s2) + (s1 + s3);
    u64 key = ((u64)fsort(s * pv) << 32) | (u64)(63 - lane);
    #pragma unroll
    for (int off = 32; off; off >>= 1){
      u64 o = __shfl_down(key, off);
      if (o > key) key = o;
    }
    if (lane == 0) packed[b * NPIX + p] = key;
  }
}

// ---------------- final greedy on C (exact), certified + fallback ------------
// Excluded pixels: approx < tmin-12 -> exact < tmin-11.4. Cert: v10_final >=
// tmin-10 > tmin-11.4 >= any excluded value -> run == full exact run.
__global__ __launch_bounds__(1024) void greedy_sl(
    const u64* __restrict__ packed, const float* __restrict__ prior,
    const u32* __restrict__ nc16, const u32* __restrict__ cand2,
    const float* __restrict__ tmin, float* __restrict__ out)
{
  const int b = blockIdx.x;
  const int tid = threadIdx.x;
  const u64* pb = packed + b * NPIX;
  const int n = (int)min(nc16[8 + b], (u32)CAP2);

  int cp[4]; float cv[4];
  #pragma unroll
  for (int k = 0; k < 4; ++k){
    int idx = tid + k * 1024;
    if (idx < n){ cp[k] = (int)cand2[b * CAP2 + idx]; cv[k] = funsort((u32)(pb[cp[k]] >> 32)); }
    else        { cp[k] = 0; cv[k] = -3e38f; }
  }

  __shared__ u64 warr[16];
  __shared__ int spx, spy, okf;
  __shared__ float v10s;
  if (tid == 0){ spx = -100000; spy = -100000; }
  __syncthreads();

  for (int t = 0; t < 10; ++t){
    const int px = spx, py = spy;
    if (px >= 0){
      #pragma unroll
      for (int k = 0; k < 4; ++k){
        if (tid + k * 1024 < n){
          float dx = (float)((cp[k] >> 8) - px), dy = (float)((cp[k] & 255) - py);
          float d2 = dx * dx + dy * dy;
          float tmap = 1.f - __expf(d2 * -0.03125f);
          if (d2 <= 16.f) tmap = 0.f;
          cv[k] *= tmap;
        }
      }
    }
    u64 key = 0ull;
    #pragma unroll
    for (int k = 0; k < 4; ++k){
      u64 kk = ((u64)fsort(cv[k]) << 32) | (u64)(0xFFFFu ^ (u32)cp[k]);
      if (kk > key) key = kk;
    }
    #pragma unroll
    for (int off = 32; off; off >>= 1){
      u64 o = __shfl_down(key, off);
      if (o > key) key = o;
    }
    if ((tid & 63) == 0) warr[tid >> 6] = key;
    __syncthreads();
    if (tid < 64){
      u64 k2 = (tid < 16) ? warr[tid] : 0ull;
      #pragma unroll
      for (int off = 8; off; off >>= 1){
        u64 o = __shfl_down(k2, off);
        if (o > k2) k2 = o;
      }
      if (tid == 0){
        int id = 0xFFFF ^ (int)(k2 & 0xFFFFull);
        float v = funsort((u32)(k2 >> 32));
        u64 pk = pb[id];
        int d = 63 - (int)(pk & 63ull);
        float bvv = funsort((u32)(pk >> 32));
        int xx = id >> 8, yy = id & 255;
        out[b * 30 + t * 3 + 0] = (float)d;
        out[b * 30 + t * 3 + 1] = (float)xx;
        out[b * 30 + t * 3 + 2] = (float)yy;
        out[240 + b * 20 + t * 2 + 0] = v;              // ov0 (umax==1 exact)
        out[240 + b * 20 + t * 2 + 1] = bvv / prior[d]; // ov1
        spx = xx; spy = yy;
        if (t == 9) v10s = v;
      }
    }
    __syncthreads();
  }

  if (tid == 0)
    okf = (nc16[8 + b] <= (u32)CAP2 && v10s >= tmin[b] - CERTF) ? 1 : 0;
  __syncthreads();
  if (okf) return;

  { // fallback: full-map greedy on (partially patched) map, writes out
    const int x = tid >> 2;
    const int ybase = (tid & 3) << 6;
    const int pbase = (x << 8) + ybase;
    float s[64];
    const bool rowin = (x >= 16 && x < 240);
    #pragma unroll
    for (int i2 = 0; i2 < 32; ++i2){
      uint4 two = *(const uint4*)(pb + pbase + 2 * i2);
      int y = ybase + 2 * i2;
      s[2*i2+0] = (rowin && y+0 >= 16 && y+0 < 240) ? funsort(two.y) : 0.0f;
      s[2*i2+1] = (rowin && y+1 >= 16 && y+1 < 240) ? funsort(two.w) : 0.0f;
    }
    float tm = -3e38f; int tp = pbase;
    #pragma unroll
    for (int i = 0; i < 64; ++i){
      if (s[i] > tm){ tm = s[i]; tp = pbase + i; }
    }
    if (tid == 0){ spx = -100000; spy = -100000; }
    __syncthreads();
    for (int t = 0; t < 10; ++t){
      const int px = spx, py = spy;
      if (px >= 0){
        int dxr = x - px;
        if (dxr >= -24 && dxr <= 24){
          int lo = py - 24 - ybase;
          int hi = py + 24 - ybase;
          if (lo < 64 && hi >= 0){
            float dx2 = (float)(dxr * dxr);
            tm = -3e38f; tp = pbase;
            #pragma unroll
            for (int i = 0; i < 64; ++i){
              if (i >= lo && i <= hi){
                float dy = (float)(ybase + i - py);
                float d2 = dx2 + dy * dy;
                float tmap = 1.f - __expf(d2 * -0.03125f);
                if (d2 <= 16.f) tmap = 0.f;
                s[i] *= tmap;
              }
              if (s[i] > tm){ tm = s[i]; tp = pbase + i; }
            }
          }
        }
      }
      u64 key = ((u64)fsort(tm) << 32) | (u64)(0xFFFFu ^ (u32)tp);
      #pragma unroll
      for (int off = 32; off; off >>= 1){
        u64 o = __shfl_down(key, off);
        if (o > key) key = o;
      }
      if ((tid & 63) == 0) warr[tid >> 6] = key;
      __syncthreads();
      if (tid < 64){
        u64 k2 = (tid < 16) ? warr[tid] : 0ull;
        #pragma unroll
        for (int off = 8; off; off >>= 1){
          u64 o = __shfl_down(k2, off);
          if (o > k2) k2 = o;
        }
        if (tid == 0){
          int id = 0xFFFF ^ (int)(k2 & 0xFFFFull);
          float v = funsort((u32)(k2 >> 32));
          u64 pk = pb[id];
          int d = 63 - (int)(pk & 63ull);
          float bvv = funsort((u32)(pk >> 32));
          int xx = id >> 8, yy = id & 255;
          out[b * 30 + t * 3 + 0] = (float)d;
          out[b * 30 + t * 3 + 1] = (float)xx;
          out[b * 30 + t * 3 + 2] = (float)yy;
          out[240 + b * 20 + t * 2 + 0] = v;
          out[240 + b * 20 + t * 2 + 1] = bvv / prior[d];
          spx = xx; spy = yy;
        }
      }
      __syncthreads();
    }
  }
}

extern "C" void kernel_launch(void* const* d_in, const int* in_sizes, int n_in,
                              void* d_out, int out_size, void* d_ws, size_t ws_size,
                              hipStream_t stream)
{
  const float* input = (const float*)d_in[0];
  const float* filt  = (const float*)d_in[1];
  const float* prior = (const float*)d_in[3];
  float* out = (float*)d_out;

  char* ws = (char*)d_ws;
  u64*      packed  = (u64*)(ws);                    // 4,194,304
  u32*      nc16    = (u32*)  (ws + 4194304);        // 64 B (ncand1[8], ncand2[8])
  u32*      mmax    = (u32*)  (ws + 4194368);        // 32 B
  float*    tmin    = (float*)(ws + 4194400);        // 32 B
  ushort_t* afh     = (ushort_t*)(ws + 4194432);     // 135,168
  ushort_t* acolh   = (ushort_t*)(ws + 4329600);     // 4,096
  float*    fcorner = (float*)(ws + 4333696);        // 8,192
  float*    priorR  = (float*)(ws + 4341888);        // 8,192
  u32*      cand    = (u32*)  (ws + 4350080);        // 8*8192*4 = 262,144
  float*    filtT4  = (float*)(ws + 4612224);        // 270,336
  float*    filtC   = (float*)(ws + 4882560);        // 8,448
  float*    filtT   = (float*)(ws + 4891008);        // 278,784
  u32*      cand2   = (u32*)  (ws + 5169792);        // 8*4096*4 = 131,072 -> 5,300,864

  transpose_kernel<<<18, 256, 0, stream>>>(filt, filtT, nc16, mmax);
  prep_kernel<<<64, 256, 0, stream>>>(filt, filtT, prior, afh, acolh,
                                      fcorner, priorR, filtT4, filtC);
  conv_mfma<<<dim3(64, NB), 512, 0, stream>>>(input, afh, acolh, fcorner, priorR, packed);
  bmax_kernel<<<dim3(32, NB), 256, 0, stream>>>(packed, mmax);
  collect1_kernel<<<dim3(32, NB), 256, 0, stream>>>(packed, mmax, nc16, cand);
  pregreedy_kernel<<<NB, 1024, 0, stream>>>(packed, nc16, cand, mmax, tmin);
  collect2_kernel<<<dim3(32, NB), 256, 0, stream>>>(packed, tmin, nc16, cand2);
  rerank_kernel<<<dim3(128, NB), 256, 0, stream>>>(input, filtT4, filtC, prior,
                                                   nc16, cand2, packed);
  greedy_sl<<<NB, 1024, 0, stream>>>(packed, prior, nc16, cand2, tmin, out);
}

// Round 21
// 208.228 us; speedup vs baseline: 1.5589x; 1.2692x over previous
//
#include <hip/hip_runtime.h>

typedef unsigned long long u64;
typedef unsigned int u32;
typedef unsigned short ushort_t;

using f32x16 = __attribute__((ext_vector_type(16))) float;
using f32x4  = __attribute__((ext_vector_type(4))) float;
using short8 = __attribute__((ext_vector_type(8))) short;

#define NB 8
#define NPIX 65536
#define CAND_CAP 65536
#define MARGIN 44.0f   // collect band below approx max (R10-R14 proven, 5 passes)

// monotone float<->uint order-preserving encoding
__device__ __forceinline__ u32 fsort(float f){
  u32 u = __float_as_uint(f);
  return (u & 0x80000000u) ? ~u : (u | 0x80000000u);
}
__device__ __forceinline__ float funsort(u32 s){
  u32 u = (s & 0x80000000u) ? (s ^ 0x80000000u) : ~s;
  return __uint_as_float(u);
}
// round-to-nearest-even f32 -> bf16 bits
__device__ __forceinline__ u32 rneb(float f){
  u32 x = __float_as_uint(f);
  return (x + 0x7fffu + ((x >> 16) & 1u)) >> 16;
}
__device__ __forceinline__ float bf2f(u32 h){ return __uint_as_float(h << 16); }

// ---------------- K1: LDS-tiled transpose filt[d][e] -> filtT[e][d] ---------
// Both sides coalesced; warms filt into L2/L3 for prep_kernel.
__global__ __launch_bounds__(256) void transpose_kernel(
    const float* __restrict__ filt, float* __restrict__ filtT,
    u32* __restrict__ ncand, u32* __restrict__ mmax)
{
  __shared__ float T[64][65];
  const int b = blockIdx.x;            // 0..17
  const int e0 = b * 64;
  const int ecnt = min(64, 1089 - e0);
  const int w = threadIdx.x >> 6, l = threadIdx.x & 63;
  if (b == 0 && threadIdx.x == 0) *ncand = 0u;
  if (b == 0 && threadIdx.x < 8) mmax[threadIdx.x] = 0u;
  for (int d = w; d < 64; d += 4)
    if (l < ecnt) T[d][l] = filt[d * 1089 + e0 + l];
  __syncthreads();
  for (int r = w; r < ecnt; r += 4)
    filtT[(e0 + r) * 64 + l] = T[l][r];
}

// ---------------- K2: fragment prep (filt L3-warm; filtT L2-warm) -----------
// afh[(((fy*2+kc)*2+dt)*64+lane)*8+j]: d=dt*32+(lane&31), fx=16kc+8(lane>>5)+j
// acolh[((kc*2+dt)*64+lane)*8+j]: fy=16kc+8(lane>>5)+j, fx=32
// fcorner/priorR[dt*1024+lane*16+reg]: d=dt*32+(reg&3)+8*(reg>>2)+4*(lane>>5)
// filtT4[((fy*8+q)*64+d)*4+e] / filtC[fy*64+d]: coalesced reads from filtT.
__global__ __launch_bounds__(256) void prep_kernel(
    const float* __restrict__ filt, const float* __restrict__ filtT,
    const float* __restrict__ prior,
    ushort_t* __restrict__ afh, ushort_t* __restrict__ acolh,
    float* __restrict__ fcorner, float* __restrict__ priorR,
    float* __restrict__ filtT4, float* __restrict__ filtC)
{
  int t = blockIdx.x * 256 + threadIdx.x;   // 16384 threads
  for (int i = t; i < 67584; i += 16384){
    int j = i & 7; int fidx = i >> 3; int lane = fidx & 63; int rest = fidx >> 6;
    int dt = rest & 1; int kc = (rest >> 1) & 1; int fy = rest >> 2;
    int d = dt * 32 + (lane & 31);
    int fx = 16 * kc + 8 * (lane >> 5) + j;
    afh[i] = (ushort_t)rneb(filt[d * 1089 + fy * 33 + fx]);
  }
  for (int i = t; i < 2048; i += 16384){
    int j = i & 7; int fidx = i >> 3; int lane = fidx & 63; int rest = fidx >> 6;
    int dt = rest & 1; int kc = rest >> 1;
    int d = dt * 32 + (lane & 31);
    int fy = 16 * kc + 8 * (lane >> 5) + j;
    acolh[i] = (ushort_t)rneb(filt[d * 1089 + fy * 33 + 32]);
  }
  for (int i = t; i < 2048; i += 16384){
    int reg = i & 15; int rest = i >> 4; int lane = rest & 63; int dt = rest >> 6;
    int d = dt * 32 + (reg & 3) + 8 * (reg >> 2) + 4 * (lane >> 5);
    fcorner[i] = filt[d * 1089 + 1088];
    priorR[i] = prior[d];
  }
  for (int i = t; i < 67584; i += 16384){   // filtT4 from filtT (coalesced)
    int e = i & 3; int d = (i >> 2) & 63; int q = (i >> 8) & 7; int fy = i >> 11;
    filtT4[i] = filtT[(fy * 33 + 4 * q + e) * 64 + d];
  }
  for (int i = t; i < 2112; i += 16384){    // filtC from filtT (coalesced)
    int d = i & 63; int fy = i >> 6;
    filtC[i] = filtT[(fy * 33 + 32) * 64 + d];
  }
}

// ---------------- conv via MFMA (pure bf16 + exact rerank downstream) -------
__device__ __forceinline__ u32 funnel(u32 hi, u32 lo, int sh){
  return (u32)((((u64)hi << 32) | (u64)lo) >> sh);
}
template<int J>
__device__ __forceinline__ short8 extractf(uint4 P0, uint4 P1, int sh){
  u32 W[8] = {P0.x, P0.y, P0.z, P0.w, P1.x, P1.y, P1.z, P1.w};
  uint4 t;
  t.x = funnel(W[J + 1], W[J + 0], sh);
  t.y = funnel(W[J + 2], W[J + 1], sh);
  t.z = funnel(W[J + 3], W[J + 2], sh);
  t.w = funnel(W[J + 4], W[J + 3], sh);
  return __builtin_bit_cast(short8, t);
}
__device__ __forceinline__ f32x16 zero16(){
  f32x16 v;
  #pragma unroll
  for (int i = 0; i < 16; ++i) v[i] = 0.f;
  return v;
}

// LDS: hi rows [36][256] bf16, row stride 512B. Block = 4-row x 256-col stripe.
// Rolling 2-row raw-uint4 register window (parity slots, static idx).
// KEEP EXACT: R11's cross-loop live km + setprio spilled (conv 82->116us).
template<int J>
__device__ __forceinline__ void conv_body(
    const char* ldsc, const ushort_t* lds16, int w, int l, int tX,
    const short8* __restrict__ afh8, const short8* __restrict__ acol8,
    const f32x4* __restrict__ fcp, const f32x4* __restrict__ prp,
    u64* __restrict__ pb, int sh)
{
  const int c = l & 31, h = l >> 5;
  const int y0 = w;                 // 0..7; pixels y = y0 + 8c
  int cob0[2], cob1[2];
  #pragma unroll
  for (int kc = 0; kc < 2; ++kc){
    int yp = (y0 + 8 * c + 16 * kc + 8 * h - 16) & 255;
    int b0 = yp >> 3, b1 = (b0 + 1) & 31;
    cob0[kc] = b0 * 16; cob1[kc] = b1 * 16;
  }
  const int cc = (y0 + 8 * c + 16) & 255;   // column-pass / corner col

#define LA(DST, FY)                                                           \
  { _Pragma("unroll")                                                         \
    for (int kc = 0; kc < 2; ++kc)                                            \
      _Pragma("unroll")                                                       \
      for (int dt = 0; dt < 2; ++dt)                                          \
        DST[kc][dt] = afh8[(((FY) * 2 + kc) * 2 + dt) * 64 + l]; }

#define LW(S, ROWI)                                                           \
  { const char* rb_ = ldsc + (ROWI) * 512;                                    \
    s##S##k0p0 = *(const uint4*)(rb_ + cob0[0]);                              \
    s##S##k0p1 = *(const uint4*)(rb_ + cob1[0]);                              \
    s##S##k1p0 = *(const uint4*)(rb_ + cob0[1]);                              \
    s##S##k1p1 = *(const uint4*)(rb_ + cob1[1]); }

#define CPH(SA, SB, ACUR, ANXT, FYP, DOPF)                                    \
  { if (DOPF){ LA(ANXT, FYP) }                                                \
    short8 b0k0 = extractf<J>(s##SA##k0p0, s##SA##k0p1, sh);                  \
    short8 b0k1 = extractf<J>(s##SA##k1p0, s##SA##k1p1, sh);                  \
    short8 b1k0 = extractf<J>(s##SB##k0p0, s##SB##k0p1, sh);                  \
    short8 b1k1 = extractf<J>(s##SB##k1p0, s##SB##k1p1, sh);                  \
    acc[0][0] = __builtin_amdgcn_mfma_f32_32x32x16_bf16(ACUR[0][0], b0k0, acc[0][0], 0, 0, 0); \
    acc[0][0] = __builtin_amdgcn_mfma_f32_32x32x16_bf16(ACUR[1][0], b0k1, acc[0][0], 0, 0, 0); \
    acc[0][1] = __builtin_amdgcn_mfma_f32_32x32x16_bf16(ACUR[0][1], b0k0, acc[0][1], 0, 0, 0); \
    acc[0][1] = __builtin_amdgcn_mfma_f32_32x32x16_bf16(ACUR[1][1], b0k1, acc[0][1], 0, 0, 0); \
    acc[1][0] = __builtin_amdgcn_mfma_f32_32x32x16_bf16(ACUR[0][0], b1k0, acc[1][0], 0, 0, 0); \
    acc[1][0] = __builtin_amdgcn_mfma_f32_32x32x16_bf16(ACUR[1][0], b1k1, acc[1][0], 0, 0, 0); \
    acc[1][1] = __builtin_amdgcn_mfma_f32_32x32x16_bf16(ACUR[0][1], b1k0, acc[1][1], 0, 0, 0); \
    acc[1][1] = __builtin_amdgcn_mfma_f32_32x32x16_bf16(ACUR[1][1], b1k1, acc[1][1], 0, 0, 0); }

  for (int g0 = 0; g0 < 2; ++g0){
    const int r0 = g0 * 2;                  // output rows r0, r0+1
    f32x16 acc[2][2];                       // [nr][dt]
    #pragma unroll
    for (int nr = 0; nr < 2; ++nr)
      #pragma unroll
      for (int dt = 0; dt < 2; ++dt) acc[nr][dt] = zero16();

    uint4 s0k0p0, s0k0p1, s0k1p0, s0k1p1;   // window slot 0 (even fy row)
    uint4 s1k0p0, s1k0p1, s1k1p0, s1k1p1;   // window slot 1 (odd fy row)
    short8 aA[2][2], aB[2][2];              // A-frag double buffer [kc][dt]

    LW(0, r0)
    LW(1, r0 + 1)
    LA(aA, 0)

    #pragma unroll 1
    for (int fy2 = 0; fy2 < 32; fy2 += 2){
      CPH(0, 1, aA, aB, fy2 + 1, true)      // fy = fy2   (rows fy2, fy2+1)
      LW(0, r0 + fy2 + 2)
      CPH(1, 0, aB, aA, fy2 + 2, true)      // fy = fy2+1 (rows fy2+1, fy2+2)
      LW(1, r0 + fy2 + 3)
    }
    CPH(0, 1, aA, aB, 0, false)             // fy = 32 (rows 32, 33)

    // column pass: fx = 32, k = fy (0..31)
    #pragma unroll
    for (int nr = 0; nr < 2; ++nr){
      #pragma unroll
      for (int kc = 0; kc < 2; ++kc){
        int base = (r0 + nr + 16 * kc + 8 * h) * 512 + cc * 2;
        u32 v0 = *(const ushort_t*)(ldsc + base + 0 * 512);
        u32 v1 = *(const ushort_t*)(ldsc + base + 1 * 512);
        u32 v2 = *(const ushort_t*)(ldsc + base + 2 * 512);
        u32 v3 = *(const ushort_t*)(ldsc + base + 3 * 512);
        u32 v4 = *(const ushort_t*)(ldsc + base + 4 * 512);
        u32 v5 = *(const ushort_t*)(ldsc + base + 5 * 512);
        u32 v6 = *(const ushort_t*)(ldsc + base + 6 * 512);
        u32 v7 = *(const ushort_t*)(ldsc + base + 7 * 512);
        uint4 t;
        t.x = v0 | (v1 << 16); t.y = v2 | (v3 << 16);
        t.z = v4 | (v5 << 16); t.w = v6 | (v7 << 16);
        short8 Bc = __builtin_bit_cast(short8, t);
        #pragma unroll
        for (int dt = 0; dt < 2; ++dt)
          acc[nr][dt] = __builtin_amdgcn_mfma_f32_32x32x16_bf16(
              acol8[(kc * 2 + dt) * 64 + l], Bc, acc[nr][dt], 0, 0, 0);
      }
    }

    // corner (fy=32, fx=32) + prior-scale + per-pixel best + store.
    // lanes l and l+32: same output column, complementary d-halves ->
    // combine via shfl_xor(32); single writer (h==0).
    #pragma unroll
    for (int nr = 0; nr < 2; ++nr){
      float cv = bf2f((u32)lds16[(r0 + nr + 32) * 256 + cc]);
      float bv = -3e38f; int bd = 0;
      #pragma unroll
      for (int dt = 0; dt < 2; ++dt){
        #pragma unroll
        for (int q = 0; q < 4; ++q){
          f32x4 fc4 = fcp[(dt * 64 + l) * 4 + q];
          f32x4 pr4 = prp[(dt * 64 + l) * 4 + q];
          #pragma unroll
          for (int e = 0; e < 4; ++e){
            int reg = q * 4 + e;
            float s = (acc[nr][dt][reg] + fc4[e] * cv) * pr4[e];
            int d = dt * 32 + e + 8 * q + 4 * h;
            if (s > bv || (s == bv && d < bd)){ bv = s; bd = d; }
          }
        }
      }
      int x = tX + r0 + nr;
      int y = y0 + 8 * c;
      u64 key = ((u64)fsort(bv) << 32) | (u64)(63 - bd);
      u64 other = __shfl_xor(key, 32);
      if (other > key) key = other;
      if (h == 0) pb[(x << 8) | y] = key;
    }
  }
#undef CPH
#undef LW
#undef LA
}

__global__ __launch_bounds__(512) void conv_mfma(
    const float* __restrict__ input,
    const ushort_t* __restrict__ afh, const ushort_t* __restrict__ acolh,
    const float* __restrict__ fcorner, const float* __restrict__ priorR,
    u64* __restrict__ packed)
{
  __shared__ ushort_t lds[9216];           // hi [36][256] bf16, 18 KB
  const int bS = blockIdx.x;               // stripe 0..63
  const int b  = blockIdx.y;
  const int tX = bS * 4;
  const int tid = threadIdx.x;

  const float* inb = input + b * NPIX;
  for (int k = tid; k < 1152; k += 512){   // 36 rows * 32 units
    int r = k >> 5, u = k & 31;
    int gx = (tX - 16 + r) & 255;
    const float* src = inb + (gx << 8) + (u << 3);
    float4 v1 = *(const float4*)(src);
    float4 v2 = *(const float4*)(src + 4);
    uint4 t;
    t.x = rneb(v1.x) | (rneb(v1.y) << 16);
    t.y = rneb(v1.z) | (rneb(v1.w) << 16);
    t.z = rneb(v2.x) | (rneb(v2.y) << 16);
    t.w = rneb(v2.z) | (rneb(v2.w) << 16);
    *(uint4*)((char*)lds + r * 512 + u * 16) = t;
  }
  __syncthreads();

  const int w = tid >> 6, l = tid & 63;
  u64* pb = packed + b * NPIX;
  const int sh = 16 * (w & 1);
  const char* ldsc = (const char*)lds;
  const short8* afh8 = (const short8*)afh;
  const short8* acol8 = (const short8*)acolh;
  const f32x4* fcp = (const f32x4*)fcorner;
  const f32x4* prp = (const f32x4*)priorR;

  switch ((w >> 1) & 3){
    case 0: conv_body<0>(ldsc, lds, w, l, tX, afh8, acol8, fcp, prp, pb, sh); break;
    case 1: conv_body<1>(ldsc, lds, w, l, tX, afh8, acol8, fcp, prp, pb, sh); break;
    case 2: conv_body<2>(ldsc, lds, w, l, tX, afh8, acol8, fcp, prp, pb, sh); break;
    default: conv_body<3>(ldsc, lds, w, l, tX, afh8, acol8, fcp, prp, pb, sh); break;
  }
}

// ---------------- per-batch approx max ---------------------------------------
__global__ __launch_bounds__(256) void bmax_kernel(const u64* __restrict__ packed,
                                                   u32* __restrict__ mmax){
  const int b = blockIdx.y, blk = blockIdx.x, tid = threadIdx.x;
  const u32* ph = (const u32*)(packed + b * NPIX);
  u32 m = 0;
  for (int k = tid; k < 2048; k += 256) m = max(m, ph[2 * (blk * 2048 + k) + 1]);
  __shared__ u32 red[256];
  red[tid] = m; __syncthreads();
  for (int s = 128; s > 0; s >>= 1){
    if (tid < s) red[tid] = max(red[tid], red[tid + s]);
    __syncthreads();
  }
  if (tid == 0) atomicMax(&mmax[b], red[0]);
}

// ---------------- collect: approx >= M - MARGIN, interior, global list ------
__global__ __launch_bounds__(256) void collect_kernel(const u64* __restrict__ packed,
    const u32* __restrict__ mmax, u32* __restrict__ ncand, u32* __restrict__ cand){
  const int b = blockIdx.y, blk = blockIdx.x, tid = threadIdx.x;
  u32 tu = fsort(funsort(mmax[b]) - MARGIN);
  const u32* ph = (const u32*)(packed + b * NPIX);
  for (int k = tid; k < 2048; k += 256){
    int p = blk * 2048 + k;
    int px = p >> 8, py = p & 255;
    u32 v = ph[2 * p + 1];
    if (v >= tu && px >= 16 && px < 240 && py >= 16 && py < 240){
      u32 slot = atomicAdd(ncand, 1u);
      if (slot < CAND_CAP) cand[slot] = ((u32)b << 16) | (u32)p;
    }
  }
}

// ---------------- exact fp32 recompute for candidates (R13 structure) --------
// Global grid-stride list, 1 cand/wave, 4096 wave slots; lane=d; filtT4
// coalesced dwordx4; input rows wave-uniform broadcast.
__global__ __launch_bounds__(256) void rerank_kernel(
    const float* __restrict__ input, const float* __restrict__ filtT4,
    const float* __restrict__ filtC, const float* __restrict__ prior,
    const u32* __restrict__ ncand, const u32* __restrict__ cand,
    u64* __restrict__ packed)
{
  const int lane = threadIdx.x & 63;       // = d
  const int wv = threadIdx.x >> 6;         // wave 0..3
  int n = (int)min(*ncand, (u32)CAND_CAP);
  float pv = prior[lane];
  for (int i = blockIdx.x * 4 + wv; i < n; i += 4096){
    u32 v = cand[i];
    int b = v >> 16, p = v & 0xffff;
    int px = p >> 8;
    int yc = (p & 255) - 16;
    float s0 = 0.f, s1 = 0.f, s2 = 0.f, s3 = 0.f;
    for (int fy = 0; fy < 33; ++fy){
      const float* ir = input + b * NPIX + ((px + fy - 16) << 8) + yc;
      const float* ft = filtT4 + fy * 2048 + lane * 4;
      #pragma unroll
      for (int q = 0; q < 8; ++q){
        const float4 fv = *(const float4*)(ft + q * 256);
        s0 = fmaf(fv.x, ir[4*q+0], s0);
        s1 = fmaf(fv.y, ir[4*q+1], s1);
        s2 = fmaf(fv.z, ir[4*q+2], s2);
        s3 = fmaf(fv.w, ir[4*q+3], s3);
      }
      s0 = fmaf(filtC[fy * 64 + lane], ir[32], s0);
    }
    float s = (s0 + s2) + (s1 + s3);
    u64 key = ((u64)fsort(s * pv) << 32) | (u64)(63 - lane);
    #pragma unroll
    for (int off = 32; off; off >>= 1){
      u64 o = __shfl_down(key, off);
      if (o > key) key = o;
    }
    if (lane == 0) packed[b * NPIX + p] = key;
  }
}

// ---------------- full-map greedy (exact; single pass) -----------------------
// 1-exp(-d2/32) == 1.0f exactly for d2 > 554.5 -> picks only perturb 49x49
// patches; 10 discs can't cover the 224x224 interior -> max(u)==1.0 exactly,
// reference normalization is an exact no-op. s in registers; dirty-region
// incremental update; wave-shfl reduction.
__global__ __launch_bounds__(1024) void greedy_kernel(
    const u64* __restrict__ packed, const float* __restrict__ prior,
    float* __restrict__ out)
{
  const int b = blockIdx.x;
  const int tid = threadIdx.x;
  const u64* pb = packed + b * NPIX;

  const int x = tid >> 2;                 // owned image row
  const int ybase = (tid & 3) << 6;       // 64-col segment
  const int pbase = (x << 8) + ybase;

  float s[64];
  const bool rowin = (x >= 16 && x < 240);
  #pragma unroll
  for (int i2 = 0; i2 < 32; ++i2){        // 2 pixels per uint4 load
    uint4 two = *(const uint4*)(pb + pbase + 2 * i2);
    int y = ybase + 2 * i2;
    s[2*i2+0] = (rowin && y+0 >= 16 && y+0 < 240) ? funsort(two.y) : 0.0f;
    s[2*i2+1] = (rowin && y+1 >= 16 && y+1 < 240) ? funsort(two.w) : 0.0f;
  }
  float tm = -3e38f; int tp = pbase;
  #pragma unroll
  for (int i = 0; i < 64; ++i){
    if (s[i] > tm){ tm = s[i]; tp = pbase + i; }
  }

  __shared__ u64 warr[16];
  __shared__ int spx, spy;
  if (tid == 0){ spx = -100000; spy = -100000; }
  __syncthreads();

  for (int t = 0; t < 10; ++t){
    const int px = spx, py = spy;
    if (px >= 0){
      int dxr = x - px;
      if (dxr >= -24 && dxr <= 24){
        int lo = py - 24 - ybase;
        int hi = py + 24 - ybase;
        if (lo < 64 && hi >= 0){
          float dx2 = (float)(dxr * dxr);
          tm = -3e38f; tp = pbase;
          #pragma unroll
          for (int i = 0; i < 64; ++i){
            if (i >= lo && i <= hi){
              float dy = (float)(ybase + i - py);
              float d2 = dx2 + dy * dy;
              float tmap = 1.f - __expf(d2 * -0.03125f);
              if (d2 <= 16.f) tmap = 0.f;
              s[i] *= tmap;
            }
            if (s[i] > tm){ tm = s[i]; tp = pbase + i; }
          }
        }
      }
    }
    // key: [fsort(value)][~p] -> max = (max value, tie: smallest p)
    u64 key = ((u64)fsort(tm) << 32) | (u64)(0xFFFFu ^ (u32)tp);
    #pragma unroll
    for (int off = 32; off; off >>= 1){
      u64 o = __shfl_down(key, off);
      if (o > key) key = o;
    }
    if ((tid & 63) == 0) warr[tid >> 6] = key;
    __syncthreads();
    if (tid < 64){
      u64 k2 = (tid < 16) ? warr[tid] : 0ull;
      #pragma unroll
      for (int off = 8; off; off >>= 1){
        u64 o = __shfl_down(k2, off);
        if (o > k2) k2 = o;
      }
      if (tid == 0){
        int id = 0xFFFF ^ (int)(k2 & 0xFFFFull);
        float v = funsort((u32)(k2 >> 32));
        u64 pk = pb[id];
        int d = 63 - (int)(pk & 63ull);
        float bvv = funsort((u32)(pk >> 32));
        int xx = id >> 8, yy = id & 255;
        out[b * 30 + t * 3 + 0] = (float)d;
        out[b * 30 + t * 3 + 1] = (float)xx;
        out[b * 30 + t * 3 + 2] = (float)yy;
        out[240 + b * 20 + t * 2 + 0] = v;              // ov0 (umax==1.0 exact)
        out[240 + b * 20 + t * 2 + 1] = bvv / prior[d]; // ov1
        spx = xx; spy = yy;
      }
    }
    __syncthreads();
  }
}

extern "C" void kernel_launch(void* const* d_in, const int* in_sizes, int n_in,
                              void* d_out, int out_size, void* d_ws, size_t ws_size,
                              hipStream_t stream)
{
  const float* input = (const float*)d_in[0];
  const float* filt  = (const float*)d_in[1];
  const float* prior = (const float*)d_in[3];
  float* out = (float*)d_out;

  char* ws = (char*)d_ws;
  u64*      packed  = (u64*)(ws);                    // 4,194,304
  u32*      ncand   = (u32*)  (ws + 4194304);        // 64 B
  u32*      mmax    = (u32*)  (ws + 4194368);        // 64 B
  ushort_t* afh     = (ushort_t*)(ws + 4194432);     // 135,168
  ushort_t* acolh   = (ushort_t*)(ws + 4329600);     // 4,096
  float*    fcorner = (float*)(ws + 4333696);        // 8,192
  float*    priorR  = (float*)(ws + 4341888);        // 8,192
  u32*      cand    = (u32*)  (ws + 4350080);        // 262,144
  float*    filtT4  = (float*)(ws + 4612224);        // 270,336
  float*    filtC   = (float*)(ws + 4882560);        // 8,448
  float*    filtT   = (float*)(ws + 4891008);        // 278,784 -> 5,169,792

  transpose_kernel<<<18, 256, 0, stream>>>(filt, filtT, ncand, mmax);
  prep_kernel<<<64, 256, 0, stream>>>(filt, filtT, prior, afh, acolh,
                                      fcorner, priorR, filtT4, filtC);
  conv_mfma<<<dim3(64, NB), 512, 0, stream>>>(input, afh, acolh, fcorner, priorR, packed);
  bmax_kernel<<<dim3(32, NB), 256, 0, stream>>>(packed, mmax);
  collect_kernel<<<dim3(32, NB), 256, 0, stream>>>(packed, mmax, ncand, cand);
  rerank_kernel<<<1024, 256, 0, stream>>>(input, filtT4, filtC, prior, ncand, cand, packed);
  greedy_kernel<<<NB, 1024, 0, stream>>>(packed, prior, out);
}